// Round 1
// baseline (475.717 us; speedup 1.0000x reference)
//
#include <hip/hip_runtime.h>

typedef unsigned short u16;
typedef unsigned int u32;
typedef short bf16x8 __attribute__((ext_vector_type(8)));
typedef float f32x4 __attribute__((ext_vector_type(4)));

#define DEV static __device__ __forceinline__

constexpr int CH = 16;          // n-chunks per batch for attention
constexpr int NB = 4096 / CH;   // 256 rows per chunk
constexpr float LN_EPS = 1e-5f;
constexpr float SCALE = 0.0625f; // 256^-0.5

DEV float bf2f(u32 u) { return __uint_as_float(u << 16); }
DEV u16 f2bf(float f) {
  u32 u = __float_as_uint(f);
  return (u16)((u + 0x7fffu + ((u >> 16) & 1u)) >> 16);
}
DEV u32 pk2(float a, float b) { return (u32)f2bf(a) | ((u32)f2bf(b) << 16); }

// ---------------- K0: convert weights to bf16 (WkvT transposed) ----------------
__global__ __launch_bounds__(256) void k_convert(
    const float* __restrict__ Wk, const float* __restrict__ Wv,
    const float* __restrict__ Wih, const float* __restrict__ Whh,
    const float* __restrict__ W1, const float* __restrict__ W2,
    u16* __restrict__ wkvT, u16* __restrict__ wih, u16* __restrict__ whh,
    u16* __restrict__ w1, u16* __restrict__ w2) {
  int idx = blockIdx.x * 256 + threadIdx.x;
  if (idx < 512 * 256) {                       // wkvT[n][k] = W(k,n)
    int n = idx >> 8, k = idx & 255;
    float v = (n < 256) ? Wk[k * 256 + n] : Wv[k * 256 + (n - 256)];
    wkvT[idx] = f2bf(v);
    return;
  }
  idx -= 512 * 256;
  if (idx < 256 * 768) { wih[idx] = f2bf(Wih[idx]); return; }
  idx -= 256 * 768;
  if (idx < 256 * 768) { whh[idx] = f2bf(Whh[idx]); return; }
  idx -= 256 * 768;
  if (idx < 256 * 512) { w1[idx] = f2bf(W1[idx]); return; }
  idx -= 256 * 512;
  if (idx < 512 * 256) { w2[idx] = f2bf(W2[idx]); return; }
}

// ---------------- K1: LayerNorm(inputs) -> x bf16 ----------------
__global__ __launch_bounds__(256) void k_ln(const float* __restrict__ in,
    const float* __restrict__ g, const float* __restrict__ b,
    u16* __restrict__ xbf) {
  int row = blockIdx.x * 4 + (threadIdx.x >> 6);
  int lane = threadIdx.x & 63;
  float4 v = ((const float4*)(in + (size_t)row * 256))[lane];
  float s = v.x + v.y + v.z + v.w;
  float ss = v.x * v.x + v.y * v.y + v.z * v.z + v.w * v.w;
#pragma unroll
  for (int o = 32; o; o >>= 1) { s += __shfl_xor(s, o); ss += __shfl_xor(ss, o); }
  float mean = s * (1.f / 256.f);
  float rstd = rsqrtf(ss * (1.f / 256.f) - mean * mean + LN_EPS);
  float4 gv = ((const float4*)g)[lane];
  float4 bv = ((const float4*)b)[lane];
  uint2 o;
  o.x = pk2((v.x - mean) * rstd * gv.x + bv.x, (v.y - mean) * rstd * gv.y + bv.y);
  o.y = pk2((v.z - mean) * rstd * gv.z + bv.z, (v.w - mean) * rstd * gv.w + bv.w);
  ((uint2*)(xbf + (size_t)row * 256))[lane] = o;
}

// ---------------- K2: slots init + first q ----------------
__global__ __launch_bounds__(256) void k_slots_init(
    const float* __restrict__ noise, const float* __restrict__ mu,
    const float* __restrict__ sig, const float* __restrict__ g,
    const float* __restrict__ b, const float* __restrict__ Wq,
    float* __restrict__ slots, float* __restrict__ qbuf) {
  int bs = blockIdx.x, t = threadIdx.x;
  float sg = sig[t];
  float sp = (sg > 20.f) ? sg : log1pf(expf(sg));
  sp = fminf(fmaxf(sp, 0.1f), 2.0f);
  float sl = mu[t] + sp * noise[bs * 256 + t];
  slots[bs * 256 + t] = sl;
  __shared__ float red[8];
  __shared__ float sln[256];
  float s = sl, ss = sl * sl;
#pragma unroll
  for (int o = 32; o; o >>= 1) { s += __shfl_xor(s, o); ss += __shfl_xor(ss, o); }
  int w = t >> 6;
  if ((t & 63) == 0) { red[w] = s; red[4 + w] = ss; }
  __syncthreads();
  s = red[0] + red[1] + red[2] + red[3];
  ss = red[4] + red[5] + red[6] + red[7];
  float mean = s * (1.f / 256.f);
  float rstd = rsqrtf(ss * (1.f / 256.f) - mean * mean + LN_EPS);
  sln[t] = (sl - mean) * rstd * g[t] + b[t];
  __syncthreads();
  float acc = 0.f;
  for (int d = 0; d < 256; ++d) acc += sln[d] * Wq[d * 256 + t];
  qbuf[bs * 256 + t] = acc;
}

// ---------------- KG: kv = x @ [Wk|Wv] (bf16 MFMA), k written transposed ----------------
__global__ __launch_bounds__(256) void k_gemm(
    const u16* __restrict__ X, const u16* __restrict__ Wt,
    u16* __restrict__ kT, u16* __restrict__ Vv) {
  __shared__ u16 smem[16896];   // A[0..8191], B[8192..16383] staging; bounce 128x132
  int bid = blockIdx.x;
  int mt = bid >> 2, nt = bid & 3;
  int w = threadIdx.x >> 6, lane = threadIdx.x & 63;
  int wr = w >> 1, wc = w & 1;
  f32x4 acc[4][4] = {};
  for (int ks = 0; ks < 4; ++ks) {
#pragma unroll
    for (int i = 0; i < 4; ++i) {
      int cbase = (w * 4 + i) * 64;
      int c = cbase + lane;
      int r = c >> 3;
      int swz = (c & 7) ^ (r & 7);
      const u16* srcA = X + (mt * 128 + r) * 256 + ks * 64 + swz * 8;
      const u16* srcB = Wt + (nt * 128 + r) * 256 + ks * 64 + swz * 8;
      __builtin_amdgcn_global_load_lds(
          (const __attribute__((address_space(1))) void*)srcA,
          (__attribute__((address_space(3))) void*)(smem + cbase * 8), 16, 0, 0);
      __builtin_amdgcn_global_load_lds(
          (const __attribute__((address_space(1))) void*)srcB,
          (__attribute__((address_space(3))) void*)(smem + 8192 + cbase * 8), 16, 0, 0);
    }
    __syncthreads();
#pragma unroll
    for (int kk = 0; kk < 2; ++kk) {
      bf16x8 af[4], bfr[4];
#pragma unroll
      for (int m = 0; m < 4; ++m) {
        int lrow = wr * 64 + m * 16 + (lane & 15);
        int slot = (kk * 4 + (lane >> 4)) ^ (lrow & 7);
        af[m] = *(const bf16x8*)((const char*)smem + lrow * 128 + slot * 16);
      }
#pragma unroll
      for (int n = 0; n < 4; ++n) {
        int lcol = wc * 64 + n * 16 + (lane & 15);
        int slot = (kk * 4 + (lane >> 4)) ^ (lcol & 7);
        bfr[n] = *(const bf16x8*)((const char*)smem + 16384 + lcol * 128 + slot * 16);
      }
#pragma unroll
      for (int m = 0; m < 4; ++m)
#pragma unroll
        for (int n = 0; n < 4; ++n)
          acc[m][n] = __builtin_amdgcn_mfma_f32_16x16x32_bf16(af[m], bfr[n], acc[m][n], 0, 0, 0);
    }
    __syncthreads();
  }
  int bb = (mt * 128) >> 12;
  int nb0 = (mt * 128) & 4095;
  if (nt < 2) {  // k output: transpose via LDS bounce -> kT[b][d][n]
#pragma unroll
    for (int m = 0; m < 4; ++m)
#pragma unroll
      for (int n = 0; n < 4; ++n) {
        int col = wc * 64 + n * 16 + (lane & 15);
        int r0 = wr * 64 + m * 16 + (lane >> 4) * 4;
        uint2 pk;
        pk.x = pk2(acc[m][n][0], acc[m][n][1]);
        pk.y = pk2(acc[m][n][2], acc[m][n][3]);
        *(uint2*)((char*)smem + col * 264 + r0 * 2) = pk;
      }
    __syncthreads();
    u16* outp = kT + bb * (1 << 20) + nt * 128 * 4096 + nb0;
    for (int i = 0; i < 32; ++i) {
      int dl = w * 32 + i;
      u32 val = *(const u32*)((const char*)smem + dl * 264 + lane * 4);
      *(u32*)(outp + dl * 4096 + 2 * lane) = val;
    }
  } else {       // v output: straight bounce -> Vv[b*4096+n][d]
#pragma unroll
    for (int m = 0; m < 4; ++m)
#pragma unroll
      for (int n = 0; n < 4; ++n) {
        int col = wc * 64 + n * 16 + (lane & 15);
        int r0 = wr * 64 + m * 16 + (lane >> 4) * 4;
#pragma unroll
        for (int j = 0; j < 4; ++j)
          *((u16*)((char*)smem + (r0 + j) * 264 + col * 2)) = f2bf(acc[m][n][j]);
      }
    __syncthreads();
    u16* outp = Vv + (mt * 128) * 256 + (nt - 2) * 128;
    for (int i = 0; i < 32; ++i) {
      int nl = w * 32 + i;
      u32 val = *(const u32*)((const char*)smem + nl * 264 + lane * 4);
      *(u32*)(outp + nl * 256 + 2 * lane) = val;
    }
  }
}

// ---------------- K3: attention partials (flash-style over n-chunks) ----------------
__global__ __launch_bounds__(128) void k_attn(
    const u16* __restrict__ kT, const u16* __restrict__ Vv,
    const float* __restrict__ qbuf,
    float* __restrict__ part_ml, float* __restrict__ part_upd) {
  int b = blockIdx.x >> 4, c = blockIdx.x & 15;
  int n0 = c * NB;
  int t = threadIdx.x;
  int w = t >> 6, lane = t & 63;
  __shared__ __align__(16) float qT[256][8];
  __shared__ __align__(16) float pl[NB][8];
  __shared__ float red[16];
  for (int i = t; i < 2048; i += 128) {
    int s = i >> 8, d = i & 255;
    qT[d][s] = qbuf[(b * 8 + s) * 256 + d];
  }
  __syncthreads();
  // phase 1: dots[n,s] for n = n0+2t, n0+2t+1
  float acc[8][2] = {};
  const u16* kp = kT + b * (1 << 20) + n0 + 2 * t;
#pragma unroll 8
  for (int d = 0; d < 256; ++d) {
    u32 kk = *(const u32*)(kp + d * 4096);
    float k0 = bf2f(kk & 0xffffu), k1 = bf2f(kk >> 16);
    float q8[8];
    *(float4*)q8 = *(const float4*)&qT[d][0];
    *(float4*)(q8 + 4) = *(const float4*)&qT[d][4];
#pragma unroll
    for (int s = 0; s < 8; ++s) { acc[s][0] += k0 * q8[s]; acc[s][1] += k1 * q8[s]; }
  }
  float mx[8];
#pragma unroll
  for (int s = 0; s < 8; ++s) {
    acc[s][0] *= SCALE; acc[s][1] *= SCALE;
    float lm = fmaxf(acc[s][0], acc[s][1]);
#pragma unroll
    for (int o = 32; o; o >>= 1) lm = fmaxf(lm, __shfl_xor(lm, o));
    if (lane == 0) red[w * 8 + s] = lm;
  }
  __syncthreads();
#pragma unroll
  for (int s = 0; s < 8; ++s) mx[s] = fmaxf(red[s], red[8 + s]);
  __syncthreads();
#pragma unroll
  for (int s = 0; s < 8; ++s) {
    float p0 = __expf(acc[s][0] - mx[s]);
    float p1 = __expf(acc[s][1] - mx[s]);
    pl[2 * t][s] = p0; pl[2 * t + 1][s] = p1;
    float l = p0 + p1;
#pragma unroll
    for (int o = 32; o; o >>= 1) l += __shfl_xor(l, o);
    if (lane == 0) red[w * 8 + s] = l;
  }
  __syncthreads();
  if (t < 8) {
    part_ml[(b * 16 + c) * 16 + t] = mx[t];
    part_ml[(b * 16 + c) * 16 + 8 + t] = red[t] + red[8 + t];
  }
  // phase 2: upd[s][d] partial, this thread owns d = 2t, 2t+1
  float upd[8][2] = {};
  const u16* vp = Vv + (b * 4096 + n0) * 256 + 2 * t;
#pragma unroll 4
  for (int n = 0; n < NB; ++n) {
    u32 vv = *(const u32*)(vp + n * 256);
    float v0 = bf2f(vv & 0xffffu), v1 = bf2f(vv >> 16);
    float p8[8];
    *(float4*)p8 = *(const float4*)&pl[n][0];
    *(float4*)(p8 + 4) = *(const float4*)&pl[n][4];
#pragma unroll
    for (int s = 0; s < 8; ++s) { upd[s][0] += p8[s] * v0; upd[s][1] += p8[s] * v1; }
  }
  float* up = part_upd + ((b * 16 + c) * 8) * 256 + 2 * t;
#pragma unroll
  for (int s = 0; s < 8; ++s) {
    float2 o2; o2.x = upd[s][0]; o2.y = upd[s][1];
    *(float2*)(up + s * 256) = o2;
  }
}

// ---------------- K4: combine + GRU + MLP + next-iteration q ----------------
__global__ __launch_bounds__(256) void k_update(
    const float* __restrict__ part_ml, const float* __restrict__ part_upd,
    const float* __restrict__ slots_in,
    const u16* __restrict__ wih, const u16* __restrict__ whh,
    const u16* __restrict__ w1m, const u16* __restrict__ w2m,
    const float* __restrict__ bih, const float* __restrict__ bhh,
    const float* __restrict__ b1v, const float* __restrict__ b2v,
    const float* __restrict__ gm, const float* __restrict__ bm,
    const float* __restrict__ gs, const float* __restrict__ bsv,
    const float* __restrict__ Wq,
    float* __restrict__ slots_out, float* __restrict__ qbuf, int write_q) {
  int bs = blockIdx.x, b = bs >> 3, s = bs & 7;
  int t = threadIdx.x, w = t >> 6, lane = t & 63;
  __shared__ float red[8];
  __shared__ float u_lds[256], h_lds[256], m_lds[256];
  __shared__ float h1_lds[512];
  // combine partials
  float M = -1e30f;
  float mv[16], lv[16];
#pragma unroll
  for (int c = 0; c < 16; ++c) {
    mv[c] = part_ml[(b * 16 + c) * 16 + s];
    lv[c] = part_ml[(b * 16 + c) * 16 + 8 + s];
    M = fmaxf(M, mv[c]);
  }
  float L = 0.f, u = 0.f;
#pragma unroll
  for (int c = 0; c < 16; ++c) {
    float wc = __expf(mv[c] - M);
    L += lv[c] * wc;
    u += part_upd[((b * 16 + c) * 8 + s) * 256 + t] * wc;
  }
  u /= L;
  u_lds[t] = u;
  float h = slots_in[bs * 256 + t];
  h_lds[t] = h;
  __syncthreads();
  // GRU gates: this thread owns dim t (cols t, 256+t, 512+t)
  float gx0 = bih[t], gx1 = bih[256 + t], gx2 = bih[512 + t];
  float gh0 = bhh[t], gh1 = bhh[256 + t], gh2 = bhh[512 + t];
  for (int d = 0; d < 256; ++d) {
    float ud = u_lds[d], hd = h_lds[d];
    gx0 += ud * bf2f(wih[d * 768 + t]);
    gx1 += ud * bf2f(wih[d * 768 + 256 + t]);
    gx2 += ud * bf2f(wih[d * 768 + 512 + t]);
    gh0 += hd * bf2f(whh[d * 768 + t]);
    gh1 += hd * bf2f(whh[d * 768 + 256 + t]);
    gh2 += hd * bf2f(whh[d * 768 + 512 + t]);
  }
  float r = 1.f / (1.f + __expf(-(gx0 + gh0)));
  float z = 1.f / (1.f + __expf(-(gx1 + gh1)));
  float ng = tanhf(gx2 + r * gh2);
  float snew = (1.f - z) * ng + z * h;
  // LN (mlp)
  float ssum = snew, ssq = snew * snew;
#pragma unroll
  for (int o = 32; o; o >>= 1) { ssum += __shfl_xor(ssum, o); ssq += __shfl_xor(ssq, o); }
  if (lane == 0) { red[w] = ssum; red[4 + w] = ssq; }
  __syncthreads();
  ssum = red[0] + red[1] + red[2] + red[3];
  ssq = red[4] + red[5] + red[6] + red[7];
  float mean = ssum * (1.f / 256.f);
  float rstd = rsqrtf(ssq * (1.f / 256.f) - mean * mean + LN_EPS);
  float mval = (snew - mean) * rstd * gm[t] + bm[t];
  m_lds[t] = mval;
  __syncthreads();
  // MLP
  float a0 = b1v[t], a1 = b1v[256 + t];
  for (int d = 0; d < 256; ++d) {
    float md = m_lds[d];
    a0 += md * bf2f(w1m[d * 512 + t]);
    a1 += md * bf2f(w1m[d * 512 + 256 + t]);
  }
  h1_lds[t] = fmaxf(a0, 0.f);
  h1_lds[256 + t] = fmaxf(a1, 0.f);
  __syncthreads();
  float o = b2v[t];
  for (int j = 0; j < 512; ++j) o += h1_lds[j] * bf2f(w2m[j * 256 + t]);
  float sout = snew + o;
  slots_out[bs * 256 + t] = sout;
  if (write_q) {
    float s2 = sout, q2 = sout * sout;
#pragma unroll
    for (int oo = 32; oo; oo >>= 1) { s2 += __shfl_xor(s2, oo); q2 += __shfl_xor(q2, oo); }
    __syncthreads();
    if (lane == 0) { red[w] = s2; red[4 + w] = q2; }
    __syncthreads();
    s2 = red[0] + red[1] + red[2] + red[3];
    q2 = red[4] + red[5] + red[6] + red[7];
    float mean2 = s2 * (1.f / 256.f);
    float rstd2 = rsqrtf(q2 * (1.f / 256.f) - mean2 * mean2 + LN_EPS);
    float sl = (sout - mean2) * rstd2 * gs[t] + bsv[t];
    m_lds[t] = sl;
    __syncthreads();
    float q = 0.f;
    for (int d = 0; d < 256; ++d) q += m_lds[d] * Wq[d * 256 + t];
    qbuf[bs * 256 + t] = q;
  }
}

extern "C" void kernel_launch(void* const* d_in, const int* in_sizes, int n_in,
                              void* d_out, int out_size, void* d_ws, size_t ws_size,
                              hipStream_t stream) {
  (void)in_sizes; (void)n_in; (void)out_size; (void)ws_size;
  const float* inputs    = (const float*)d_in[0];
  const float* noise     = (const float*)d_in[1];
  const float* ln_in_g   = (const float*)d_in[2];
  const float* ln_in_b   = (const float*)d_in[3];
  const float* ln_slot_g = (const float*)d_in[4];
  const float* ln_slot_b = (const float*)d_in[5];
  const float* ln_mlp_g  = (const float*)d_in[6];
  const float* ln_mlp_b  = (const float*)d_in[7];
  const float* slot_mu   = (const float*)d_in[8];
  const float* slot_sig  = (const float*)d_in[9];
  const float* Wq        = (const float*)d_in[10];
  const float* Wk        = (const float*)d_in[11];
  const float* Wv        = (const float*)d_in[12];
  const float* W_ih      = (const float*)d_in[13];
  const float* W_hh      = (const float*)d_in[14];
  const float* b_ih      = (const float*)d_in[15];
  const float* b_hh      = (const float*)d_in[16];
  const float* W1        = (const float*)d_in[17];
  const float* b1        = (const float*)d_in[18];
  const float* W2        = (const float*)d_in[19];
  const float* b2        = (const float*)d_in[20];

  char* p = (char*)d_ws;
  auto take = [&](size_t bytes) { char* r = p; p += (bytes + 255) & ~(size_t)255; return r; };
  u16* xbf      = (u16*)take((size_t)131072 * 256 * 2);
  u16* kT       = (u16*)take((size_t)32 * 256 * 4096 * 2);
  u16* Vv       = (u16*)take((size_t)32 * 4096 * 256 * 2);
  u16* wkvT     = (u16*)take(512 * 256 * 2);
  u16* wihb     = (u16*)take(256 * 768 * 2);
  u16* whhb     = (u16*)take(256 * 768 * 2);
  u16* w1b      = (u16*)take(256 * 512 * 2);
  u16* w2b      = (u16*)take(512 * 256 * 2);
  float* slotsA = (float*)take(256 * 256 * 4);
  float* slotsB = (float*)take(256 * 256 * 4);
  float* qbuf   = (float*)take(256 * 256 * 4);
  float* pml    = (float*)take(32 * 16 * 16 * 4);
  float* pupd   = (float*)take((size_t)32 * 16 * 8 * 256 * 4);

  k_convert<<<3072, 256, 0, stream>>>(Wk, Wv, W_ih, W_hh, W1, W2, wkvT, wihb, whhb, w1b, w2b);
  k_ln<<<32768, 256, 0, stream>>>(inputs, ln_in_g, ln_in_b, xbf);
  k_slots_init<<<256, 256, 0, stream>>>(noise, slot_mu, slot_sig, ln_slot_g, ln_slot_b, Wq, slotsA, qbuf);
  k_gemm<<<4096, 256, 0, stream>>>(xbf, wkvT, kT, Vv);

  const float* scur = slotsA;
  for (int it = 0; it < 3; ++it) {
    k_attn<<<512, 128, 0, stream>>>(kT, Vv, qbuf, pml, pupd);
    float* sout = (it == 2) ? (float*)d_out : ((it == 0) ? slotsB : slotsA);
    k_update<<<256, 256, 0, stream>>>(pml, pupd, scur, wihb, whhb, w1b, w2b,
        b_ih, b_hh, b1, b2, ln_mlp_g, ln_mlp_b, ln_slot_g, ln_slot_b, Wq,
        sout, qbuf, (it < 2) ? 1 : 0);
    scur = sout;
  }
}

// Round 2
// 407.831 us; speedup vs baseline: 1.1665x; 1.1665x over previous
//
#include <hip/hip_runtime.h>

typedef unsigned short u16;
typedef unsigned int u32;
typedef short bf16x8 __attribute__((ext_vector_type(8)));
typedef float f32x4 __attribute__((ext_vector_type(4)));

#define DEV static __device__ __forceinline__

constexpr int CH = 16;          // n-chunks per batch for attention
constexpr int NB = 4096 / CH;   // 256 rows per chunk
constexpr float LN_EPS = 1e-5f;
constexpr float SCALE = 0.0625f; // 256^-0.5

DEV float bf2f(u32 u) { return __uint_as_float(u << 16); }
DEV float bfe(short x) { return __uint_as_float(((u32)(u16)x) << 16); }
DEV u16 f2bf(float f) {
  u32 u = __float_as_uint(f);
  return (u16)((u + 0x7fffu + ((u >> 16) & 1u)) >> 16);
}
DEV u32 pk2(float a, float b) { return (u32)f2bf(a) | ((u32)f2bf(b) << 16); }

// ---------------- K0: convert weights to bf16, packed per-thread streams ----------------
// wkvT[n][k]               (512x256)   B for the k/v GEMM
// wgru[t][db][m][j]        (256x32x6x8) m: 0..2 = W_ih gate r/z/n col t, 3..5 = W_hh
// wmlp1[t][db][m][j]       (256x32x2x8) m: 0 = W1 col t, 1 = W1 col 256+t
// w2t[t][j]                (256x512)    W2 col t
// wqt[t][d]                (256x256)    Wq col t
__global__ __launch_bounds__(256) void k_convert(
    const float* __restrict__ Wk, const float* __restrict__ Wv,
    const float* __restrict__ Wih, const float* __restrict__ Whh,
    const float* __restrict__ W1, const float* __restrict__ W2,
    const float* __restrict__ Wq,
    u16* __restrict__ wkvT, u16* __restrict__ wgru, u16* __restrict__ wmlp1,
    u16* __restrict__ w2t, u16* __restrict__ wqt) {
  int idx = blockIdx.x * 256 + threadIdx.x;
  if (idx < 512 * 256) {                       // wkvT[n][k] = W(k,n)
    int n = idx >> 8, k = idx & 255;
    float v = (n < 256) ? Wk[k * 256 + n] : Wv[k * 256 + (n - 256)];
    wkvT[idx] = f2bf(v);
    return;
  }
  idx -= 512 * 256;
  if (idx < 256 * 32 * 6 * 8) {
    int t = idx / 1536;
    int r = idx % 1536;
    int db = r / 48;
    int r2 = r % 48;
    int m = r2 >> 3, j = r2 & 7;
    int d = db * 8 + j;
    float v = (m < 3) ? Wih[d * 768 + m * 256 + t] : Whh[d * 768 + (m - 3) * 256 + t];
    wgru[idx] = f2bf(v);
    return;
  }
  idx -= 256 * 32 * 6 * 8;
  if (idx < 256 * 32 * 2 * 8) {
    int t = idx / 512;
    int r = idx % 512;
    int db = r >> 4;
    int m = (r >> 3) & 1, j = r & 7;
    int d = db * 8 + j;
    wmlp1[idx] = f2bf(W1[d * 512 + m * 256 + t]);
    return;
  }
  idx -= 256 * 32 * 2 * 8;
  if (idx < 256 * 512) {                        // w2t[t][j] = W2[j][t]
    int t = idx >> 9, j = idx & 511;
    w2t[idx] = f2bf(W2[j * 256 + t]);
    return;
  }
  idx -= 256 * 512;
  if (idx < 256 * 256) {                        // wqt[t][d] = Wq[d][t]
    int t = idx >> 8, d = idx & 255;
    wqt[idx] = f2bf(Wq[d * 256 + t]);
    return;
  }
}

// ---------------- K1: LayerNorm(inputs) -> x bf16 ----------------
__global__ __launch_bounds__(256) void k_ln(const float* __restrict__ in,
    const float* __restrict__ g, const float* __restrict__ b,
    u16* __restrict__ xbf) {
  int row = blockIdx.x * 4 + (threadIdx.x >> 6);
  int lane = threadIdx.x & 63;
  float4 v = ((const float4*)(in + (size_t)row * 256))[lane];
  float s = v.x + v.y + v.z + v.w;
  float ss = v.x * v.x + v.y * v.y + v.z * v.z + v.w * v.w;
#pragma unroll
  for (int o = 32; o; o >>= 1) { s += __shfl_xor(s, o); ss += __shfl_xor(ss, o); }
  float mean = s * (1.f / 256.f);
  float rstd = rsqrtf(ss * (1.f / 256.f) - mean * mean + LN_EPS);
  float4 gv = ((const float4*)g)[lane];
  float4 bv = ((const float4*)b)[lane];
  uint2 o;
  o.x = pk2((v.x - mean) * rstd * gv.x + bv.x, (v.y - mean) * rstd * gv.y + bv.y);
  o.y = pk2((v.z - mean) * rstd * gv.z + bv.z, (v.w - mean) * rstd * gv.w + bv.w);
  ((uint2*)(xbf + (size_t)row * 256))[lane] = o;
}

// ---------------- K2: slots init + first q ----------------
__global__ __launch_bounds__(256) void k_slots_init(
    const float* __restrict__ noise, const float* __restrict__ mu,
    const float* __restrict__ sig, const float* __restrict__ g,
    const float* __restrict__ b, const u16* __restrict__ wqt,
    float* __restrict__ slots, float* __restrict__ qbuf) {
  int bs = blockIdx.x, t = threadIdx.x;
  float sg = sig[t];
  float sp = (sg > 20.f) ? sg : log1pf(expf(sg));
  sp = fminf(fmaxf(sp, 0.1f), 2.0f);
  float sl = mu[t] + sp * noise[bs * 256 + t];
  slots[bs * 256 + t] = sl;
  __shared__ float red[8];
  __shared__ __align__(16) float sln[256];
  float s = sl, ss = sl * sl;
#pragma unroll
  for (int o = 32; o; o >>= 1) { s += __shfl_xor(s, o); ss += __shfl_xor(ss, o); }
  int w = t >> 6;
  if ((t & 63) == 0) { red[w] = s; red[4 + w] = ss; }
  __syncthreads();
  s = red[0] + red[1] + red[2] + red[3];
  ss = red[4] + red[5] + red[6] + red[7];
  float mean = s * (1.f / 256.f);
  float rstd = rsqrtf(ss * (1.f / 256.f) - mean * mean + LN_EPS);
  sln[t] = (sl - mean) * rstd * g[t] + b[t];
  __syncthreads();
  float acc = 0.f;
  const bf16x8* wqp = (const bf16x8*)(wqt + t * 256);
#pragma unroll 4
  for (int db = 0; db < 32; ++db) {
    float q8[8];
    *(float4*)q8 = *(const float4*)&sln[db * 8];
    *(float4*)(q8 + 4) = *(const float4*)&sln[db * 8 + 4];
    bf16x8 wv = wqp[db];
#pragma unroll
    for (int j = 0; j < 8; ++j) acc += q8[j] * bfe(wv[j]);
  }
  qbuf[bs * 256 + t] = acc;
}

// ---------------- KG: kv = x @ [Wk|Wv] (bf16 MFMA), k written transposed ----------------
__global__ __launch_bounds__(256) void k_gemm(
    const u16* __restrict__ X, const u16* __restrict__ Wt,
    u16* __restrict__ kT, u16* __restrict__ Vv) {
  __shared__ u16 smem[16896];   // A[0..8191], B[8192..16383] staging; bounce 128x132
  int bid = blockIdx.x;
  int mt = bid >> 2, nt = bid & 3;
  int w = threadIdx.x >> 6, lane = threadIdx.x & 63;
  int wr = w >> 1, wc = w & 1;
  f32x4 acc[4][4] = {};
  for (int ks = 0; ks < 4; ++ks) {
#pragma unroll
    for (int i = 0; i < 4; ++i) {
      int cbase = (w * 4 + i) * 64;
      int c = cbase + lane;
      int r = c >> 3;
      int swz = (c & 7) ^ (r & 7);
      const u16* srcA = X + (mt * 128 + r) * 256 + ks * 64 + swz * 8;
      const u16* srcB = Wt + (nt * 128 + r) * 256 + ks * 64 + swz * 8;
      __builtin_amdgcn_global_load_lds(
          (const __attribute__((address_space(1))) void*)srcA,
          (__attribute__((address_space(3))) void*)(smem + cbase * 8), 16, 0, 0);
      __builtin_amdgcn_global_load_lds(
          (const __attribute__((address_space(1))) void*)srcB,
          (__attribute__((address_space(3))) void*)(smem + 8192 + cbase * 8), 16, 0, 0);
    }
    __syncthreads();
#pragma unroll
    for (int kk = 0; kk < 2; ++kk) {
      bf16x8 af[4], bfr[4];
#pragma unroll
      for (int m = 0; m < 4; ++m) {
        int lrow = wr * 64 + m * 16 + (lane & 15);
        int slot = (kk * 4 + (lane >> 4)) ^ (lrow & 7);
        af[m] = *(const bf16x8*)((const char*)smem + lrow * 128 + slot * 16);
      }
#pragma unroll
      for (int n = 0; n < 4; ++n) {
        int lcol = wc * 64 + n * 16 + (lane & 15);
        int slot = (kk * 4 + (lane >> 4)) ^ (lcol & 7);
        bfr[n] = *(const bf16x8*)((const char*)smem + 16384 + lcol * 128 + slot * 16);
      }
#pragma unroll
      for (int m = 0; m < 4; ++m)
#pragma unroll
        for (int n = 0; n < 4; ++n)
          acc[m][n] = __builtin_amdgcn_mfma_f32_16x16x32_bf16(af[m], bfr[n], acc[m][n], 0, 0, 0);
    }
    __syncthreads();
  }
  int bb = (mt * 128) >> 12;
  int nb0 = (mt * 128) & 4095;
  if (nt < 2) {  // k output: transpose via LDS bounce -> kT[b][d][n]
#pragma unroll
    for (int m = 0; m < 4; ++m)
#pragma unroll
      for (int n = 0; n < 4; ++n) {
        int col = wc * 64 + n * 16 + (lane & 15);
        int r0 = wr * 64 + m * 16 + (lane >> 4) * 4;
        uint2 pk;
        pk.x = pk2(acc[m][n][0], acc[m][n][1]);
        pk.y = pk2(acc[m][n][2], acc[m][n][3]);
        *(uint2*)((char*)smem + col * 264 + r0 * 2) = pk;
      }
    __syncthreads();
    u16* outp = kT + bb * (1 << 20) + nt * 128 * 4096 + nb0;
    for (int i = 0; i < 32; ++i) {
      int dl = w * 32 + i;
      u32 val = *(const u32*)((const char*)smem + dl * 264 + lane * 4);
      *(u32*)(outp + dl * 4096 + 2 * lane) = val;
    }
  } else {       // v output: straight bounce -> Vv[b*4096+n][d]
#pragma unroll
    for (int m = 0; m < 4; ++m)
#pragma unroll
      for (int n = 0; n < 4; ++n) {
        int col = wc * 64 + n * 16 + (lane & 15);
        int r0 = wr * 64 + m * 16 + (lane >> 4) * 4;
#pragma unroll
        for (int j = 0; j < 4; ++j)
          *((u16*)((char*)smem + (r0 + j) * 264 + col * 2)) = f2bf(acc[m][n][j]);
      }
    __syncthreads();
    u16* outp = Vv + (mt * 128) * 256 + (nt - 2) * 128;
    for (int i = 0; i < 32; ++i) {
      int nl = w * 32 + i;
      u32 val = *(const u32*)((const char*)smem + nl * 264 + lane * 4);
      *(u32*)(outp + nl * 256 + 2 * lane) = val;
    }
  }
}

// ---------------- K3: attention partials (flash-style over n-chunks) ----------------
__global__ __launch_bounds__(128) void k_attn(
    const u16* __restrict__ kT, const u16* __restrict__ Vv,
    const float* __restrict__ qbuf,
    float* __restrict__ part_ml, float* __restrict__ part_upd) {
  int b = blockIdx.x >> 4, c = blockIdx.x & 15;
  int n0 = c * NB;
  int t = threadIdx.x;
  int w = t >> 6, lane = t & 63;
  __shared__ __align__(16) float qT[256][8];
  __shared__ __align__(16) float pl[NB][8];
  __shared__ float red[16];
  for (int i = t; i < 2048; i += 128) {
    int s = i >> 8, d = i & 255;
    qT[d][s] = qbuf[(b * 8 + s) * 256 + d];
  }
  __syncthreads();
  // phase 1: dots[n,s] for n = n0+2t, n0+2t+1
  float acc[8][2] = {};
  const u16* kp = kT + b * (1 << 20) + n0 + 2 * t;
#pragma unroll 8
  for (int d = 0; d < 256; ++d) {
    u32 kk = *(const u32*)(kp + d * 4096);
    float k0 = bf2f(kk & 0xffffu), k1 = bf2f(kk >> 16);
    float q8[8];
    *(float4*)q8 = *(const float4*)&qT[d][0];
    *(float4*)(q8 + 4) = *(const float4*)&qT[d][4];
#pragma unroll
    for (int s = 0; s < 8; ++s) { acc[s][0] += k0 * q8[s]; acc[s][1] += k1 * q8[s]; }
  }
  float mx[8];
#pragma unroll
  for (int s = 0; s < 8; ++s) {
    acc[s][0] *= SCALE; acc[s][1] *= SCALE;
    float lm = fmaxf(acc[s][0], acc[s][1]);
#pragma unroll
    for (int o = 32; o; o >>= 1) lm = fmaxf(lm, __shfl_xor(lm, o));
    if (lane == 0) red[w * 8 + s] = lm;
  }
  __syncthreads();
#pragma unroll
  for (int s = 0; s < 8; ++s) mx[s] = fmaxf(red[s], red[8 + s]);
  __syncthreads();
#pragma unroll
  for (int s = 0; s < 8; ++s) {
    float p0 = __expf(acc[s][0] - mx[s]);
    float p1 = __expf(acc[s][1] - mx[s]);
    pl[2 * t][s] = p0; pl[2 * t + 1][s] = p1;
    float l = p0 + p1;
#pragma unroll
    for (int o = 32; o; o >>= 1) l += __shfl_xor(l, o);
    if (lane == 0) red[w * 8 + s] = l;
  }
  __syncthreads();
  if (t < 8) {
    part_ml[(b * 16 + c) * 16 + t] = mx[t];
    part_ml[(b * 16 + c) * 16 + 8 + t] = red[t] + red[8 + t];
  }
  // phase 2: upd[s][d] partial, this thread owns d = 2t, 2t+1
  float upd[8][2] = {};
  const u16* vp = Vv + (b * 4096 + n0) * 256 + 2 * t;
#pragma unroll 4
  for (int n = 0; n < NB; ++n) {
    u32 vv = *(const u32*)(vp + n * 256);
    float v0 = bf2f(vv & 0xffffu), v1 = bf2f(vv >> 16);
    float p8[8];
    *(float4*)p8 = *(const float4*)&pl[n][0];
    *(float4*)(p8 + 4) = *(const float4*)&pl[n][4];
#pragma unroll
    for (int s = 0; s < 8; ++s) { upd[s][0] += p8[s] * v0; upd[s][1] += p8[s] * v1; }
  }
  float* up = part_upd + ((b * 16 + c) * 8) * 256 + 2 * t;
#pragma unroll
  for (int s = 0; s < 8; ++s) {
    float2 o2; o2.x = upd[s][0]; o2.y = upd[s][1];
    *(float2*)(up + s * 256) = o2;
  }
}

// ---------------- K4: combine + GRU + MLP + next-iteration q ----------------
__global__ __launch_bounds__(256) void k_update(
    const float* __restrict__ part_ml, const float* __restrict__ part_upd,
    const float* __restrict__ slots_in,
    const u16* __restrict__ wgru, const u16* __restrict__ wmlp1,
    const u16* __restrict__ w2t, const u16* __restrict__ wqt,
    const float* __restrict__ bih, const float* __restrict__ bhh,
    const float* __restrict__ b1v, const float* __restrict__ b2v,
    const float* __restrict__ gm, const float* __restrict__ bm,
    const float* __restrict__ gs, const float* __restrict__ bsv,
    float* __restrict__ slots_out, float* __restrict__ qbuf, int write_q) {
  int bs = blockIdx.x, b = bs >> 3, s = bs & 7;
  int t = threadIdx.x, w = t >> 6, lane = t & 63;
  __shared__ float red[8];
  __shared__ __align__(16) float u_lds[256], h_lds[256], m_lds[256];
  __shared__ __align__(16) float h1_lds[512];
  // combine partials
  float M = -1e30f;
  float mv[16], lv[16];
#pragma unroll
  for (int c = 0; c < 16; ++c) {
    mv[c] = part_ml[(b * 16 + c) * 16 + s];
    lv[c] = part_ml[(b * 16 + c) * 16 + 8 + s];
    M = fmaxf(M, mv[c]);
  }
  float L = 0.f, u = 0.f;
#pragma unroll
  for (int c = 0; c < 16; ++c) {
    float wc = __expf(mv[c] - M);
    L += lv[c] * wc;
    u += part_upd[((b * 16 + c) * 8 + s) * 256 + t] * wc;
  }
  u /= L;
  u_lds[t] = u;
  float h = slots_in[bs * 256 + t];
  h_lds[t] = h;
  __syncthreads();
  // GRU gates: thread t owns output cols t, 256+t, 512+t; packed weight stream
  float gx0 = bih[t], gx1 = bih[256 + t], gx2 = bih[512 + t];
  float gh0 = bhh[t], gh1 = bhh[256 + t], gh2 = bhh[512 + t];
  const bf16x8* wg = (const bf16x8*)(wgru + t * 1536);
#pragma unroll 4
  for (int db = 0; db < 32; ++db) {
    float uu[8], hh[8];
    *(float4*)uu = *(const float4*)&u_lds[db * 8];
    *(float4*)(uu + 4) = *(const float4*)&u_lds[db * 8 + 4];
    *(float4*)hh = *(const float4*)&h_lds[db * 8];
    *(float4*)(hh + 4) = *(const float4*)&h_lds[db * 8 + 4];
    bf16x8 w0 = wg[db * 6], w1v = wg[db * 6 + 1], w2v = wg[db * 6 + 2];
    bf16x8 w3 = wg[db * 6 + 3], w4 = wg[db * 6 + 4], w5 = wg[db * 6 + 5];
#pragma unroll
    for (int j = 0; j < 8; ++j) {
      gx0 += uu[j] * bfe(w0[j]);
      gx1 += uu[j] * bfe(w1v[j]);
      gx2 += uu[j] * bfe(w2v[j]);
      gh0 += hh[j] * bfe(w3[j]);
      gh1 += hh[j] * bfe(w4[j]);
      gh2 += hh[j] * bfe(w5[j]);
    }
  }
  float r = 1.f / (1.f + __expf(-(gx0 + gh0)));
  float z = 1.f / (1.f + __expf(-(gx1 + gh1)));
  float ng = tanhf(gx2 + r * gh2);
  float snew = (1.f - z) * ng + z * h;
  // LN (mlp)
  float ssum = snew, ssq = snew * snew;
#pragma unroll
  for (int o = 32; o; o >>= 1) { ssum += __shfl_xor(ssum, o); ssq += __shfl_xor(ssq, o); }
  if (lane == 0) { red[w] = ssum; red[4 + w] = ssq; }
  __syncthreads();
  ssum = red[0] + red[1] + red[2] + red[3];
  ssq = red[4] + red[5] + red[6] + red[7];
  float mean = ssum * (1.f / 256.f);
  float rstd = rsqrtf(ssq * (1.f / 256.f) - mean * mean + LN_EPS);
  float mval = (snew - mean) * rstd * gm[t] + bm[t];
  m_lds[t] = mval;
  __syncthreads();
  // MLP layer 1: thread t owns hidden cols t, 256+t
  float a0 = b1v[t], a1 = b1v[256 + t];
  const bf16x8* wm = (const bf16x8*)(wmlp1 + t * 512);
#pragma unroll 4
  for (int db = 0; db < 32; ++db) {
    float mm[8];
    *(float4*)mm = *(const float4*)&m_lds[db * 8];
    *(float4*)(mm + 4) = *(const float4*)&m_lds[db * 8 + 4];
    bf16x8 wA = wm[db * 2], wB = wm[db * 2 + 1];
#pragma unroll
    for (int j = 0; j < 8; ++j) {
      a0 += mm[j] * bfe(wA[j]);
      a1 += mm[j] * bfe(wB[j]);
    }
  }
  h1_lds[t] = fmaxf(a0, 0.f);
  h1_lds[256 + t] = fmaxf(a1, 0.f);
  __syncthreads();
  // MLP layer 2: thread t owns output col t
  float o = b2v[t];
  const bf16x8* w2p = (const bf16x8*)(w2t + t * 512);
#pragma unroll 4
  for (int jb = 0; jb < 64; ++jb) {
    float hv[8];
    *(float4*)hv = *(const float4*)&h1_lds[jb * 8];
    *(float4*)(hv + 4) = *(const float4*)&h1_lds[jb * 8 + 4];
    bf16x8 wv = w2p[jb];
#pragma unroll
    for (int j = 0; j < 8; ++j) o += hv[j] * bfe(wv[j]);
  }
  float sout = snew + o;
  slots_out[bs * 256 + t] = sout;
  if (write_q) {
    float s2 = sout, q2 = sout * sout;
#pragma unroll
    for (int oo = 32; oo; oo >>= 1) { s2 += __shfl_xor(s2, oo); q2 += __shfl_xor(q2, oo); }
    __syncthreads();
    if (lane == 0) { red[w] = s2; red[4 + w] = q2; }
    __syncthreads();
    s2 = red[0] + red[1] + red[2] + red[3];
    q2 = red[4] + red[5] + red[6] + red[7];
    float mean2 = s2 * (1.f / 256.f);
    float rstd2 = rsqrtf(q2 * (1.f / 256.f) - mean2 * mean2 + LN_EPS);
    float sl = (sout - mean2) * rstd2 * gs[t] + bsv[t];
    m_lds[t] = sl;
    __syncthreads();
    float q = 0.f;
    const bf16x8* wqp = (const bf16x8*)(wqt + t * 256);
#pragma unroll 4
    for (int db = 0; db < 32; ++db) {
      float q8[8];
      *(float4*)q8 = *(const float4*)&m_lds[db * 8];
      *(float4*)(q8 + 4) = *(const float4*)&m_lds[db * 8 + 4];
      bf16x8 wv = wqp[db];
#pragma unroll
      for (int j = 0; j < 8; ++j) q += q8[j] * bfe(wv[j]);
    }
    qbuf[bs * 256 + t] = q;
  }
}

extern "C" void kernel_launch(void* const* d_in, const int* in_sizes, int n_in,
                              void* d_out, int out_size, void* d_ws, size_t ws_size,
                              hipStream_t stream) {
  (void)in_sizes; (void)n_in; (void)out_size; (void)ws_size;
  const float* inputs    = (const float*)d_in[0];
  const float* noise     = (const float*)d_in[1];
  const float* ln_in_g   = (const float*)d_in[2];
  const float* ln_in_b   = (const float*)d_in[3];
  const float* ln_slot_g = (const float*)d_in[4];
  const float* ln_slot_b = (const float*)d_in[5];
  const float* ln_mlp_g  = (const float*)d_in[6];
  const float* ln_mlp_b  = (const float*)d_in[7];
  const float* slot_mu   = (const float*)d_in[8];
  const float* slot_sig  = (const float*)d_in[9];
  const float* Wq        = (const float*)d_in[10];
  const float* Wk        = (const float*)d_in[11];
  const float* Wv        = (const float*)d_in[12];
  const float* W_ih      = (const float*)d_in[13];
  const float* W_hh      = (const float*)d_in[14];
  const float* b_ih      = (const float*)d_in[15];
  const float* b_hh      = (const float*)d_in[16];
  const float* W1        = (const float*)d_in[17];
  const float* b1        = (const float*)d_in[18];
  const float* W2        = (const float*)d_in[19];
  const float* b2        = (const float*)d_in[20];

  char* p = (char*)d_ws;
  auto take = [&](size_t bytes) { char* r = p; p += (bytes + 255) & ~(size_t)255; return r; };
  u16* xbf      = (u16*)take((size_t)131072 * 256 * 2);
  u16* kT       = (u16*)take((size_t)32 * 256 * 4096 * 2);
  u16* Vv       = (u16*)take((size_t)32 * 4096 * 256 * 2);
  u16* wkvT     = (u16*)take(512 * 256 * 2);
  u16* wgru     = (u16*)take(256 * 32 * 6 * 8 * 2);
  u16* wmlp1    = (u16*)take(256 * 32 * 2 * 8 * 2);
  u16* w2t      = (u16*)take(256 * 512 * 2);
  u16* wqt      = (u16*)take(256 * 256 * 2);
  float* slotsA = (float*)take(256 * 256 * 4);
  float* slotsB = (float*)take(256 * 256 * 4);
  float* qbuf   = (float*)take(256 * 256 * 4);
  float* pml    = (float*)take(32 * 16 * 16 * 4);
  float* pupd   = (float*)take((size_t)32 * 16 * 8 * 256 * 4);

  k_convert<<<3328, 256, 0, stream>>>(Wk, Wv, W_ih, W_hh, W1, W2, Wq,
                                      wkvT, wgru, wmlp1, w2t, wqt);
  k_ln<<<32768, 256, 0, stream>>>(inputs, ln_in_g, ln_in_b, xbf);
  k_slots_init<<<256, 256, 0, stream>>>(noise, slot_mu, slot_sig, ln_slot_g, ln_slot_b, wqt, slotsA, qbuf);
  k_gemm<<<4096, 256, 0, stream>>>(xbf, wkvT, kT, Vv);

  const float* scur = slotsA;
  for (int it = 0; it < 3; ++it) {
    k_attn<<<512, 128, 0, stream>>>(kT, Vv, qbuf, pml, pupd);
    float* sout = (it == 2) ? (float*)d_out : ((it == 0) ? slotsB : slotsA);
    k_update<<<256, 256, 0, stream>>>(pml, pupd, scur, wgru, wmlp1, w2t, wqt,
        b_ih, b_hh, b1, b2, ln_mlp_g, ln_mlp_b, ln_slot_g, ln_slot_b,
        sout, qbuf, (it < 2) ? 1 : 0);
    scur = sout;
  }
}